// Round 2
// baseline (7806.731 us; speedup 1.0000x reference)
//
#include <hip/hip_runtime.h>
#include <cstddef>

#define Pp    3
#define Cc    64
#define IMGi  48
#define Gg    16
#define Dd    576
#define NHh   12
#define HDd   48
#define HIDh  2304
#define NLl   4
#define Ss    256
#define Bb    4
#define Mm    1024          // S*B tokens
#define EPSf  1e-5f
#define NJOBS 43

struct QJobs { const float* ptr[NJOBS]; int n[NJOBS]; };

// ---------------- small utility kernels ----------------

__global__ void k_zero(float* p, int n) {
  int i = blockIdx.x * blockDim.x + threadIdx.x;
  if (i < n) p[i] = 0.f;
}

__global__ void k_abssum(QJobs jobs, float* absum) {
  int job = blockIdx.x >> 6, blk = blockIdx.x & 63;
  const float* p = jobs.ptr[job];
  int n = jobs.n[job];
  float s = 0.f;
  for (int i = blk * 256 + threadIdx.x; i < n; i += 64 * 256)
    s += fabsf(p[i]);
  __shared__ float red[256];
  red[threadIdx.x] = s; __syncthreads();
  for (int o = 128; o > 0; o >>= 1) {
    if (threadIdx.x < o) red[threadIdx.x] += red[threadIdx.x + o];
    __syncthreads();
  }
  if (threadIdx.x == 0) atomicAdd(&absum[job], red[0]);
}

__global__ void k_alpha(QJobs jobs, const float* absum, float* alpha) {
  int j = threadIdx.x;
  if (j < NJOBS) alpha[j] = 2.f * (absum[j] / (float)jobs.n[j]) / sqrtf(7.f);
}

// x:(B,C,48,48) fp32 -> t:(S,B,D) fp32 ; row = s*B+b
__global__ void k_patchify(const float* __restrict__ x, float* __restrict__ t) {
  int i = blockIdx.x * 256 + threadIdx.x;
  if (i >= Mm * Dd) return;
  int d = i % Dd, row = i / Dd;
  int b = row % Bb, s = row / Bb;
  int c = d / 9, r = d % 9;
  int p1 = r / 3, p2 = r % 3;
  int g1 = s / Gg, g2 = s % Gg;
  t[i] = x[((size_t)(b * Cc + c) * IMGi + (g1 * Pp + p1)) * IMGi + (g2 * Pp + p2)];
}

__global__ void k_add_pos(float* __restrict__ h, const float* __restrict__ pos) {
  int i = blockIdx.x * 256 + threadIdx.x;
  if (i >= Mm * Dd) return;
  int d = i % Dd, s = (i / Dd) / Bb;
  h[i] += pos[(size_t)s * Dd + d];
}

__global__ void k_add_qe(const float* __restrict__ x, const float* __restrict__ qew,
                         const int* __restrict__ qidx, float* __restrict__ y) {
  int i = blockIdx.x * 256 + threadIdx.x;
  if (i >= Mm * Dd) return;
  int d = i % Dd, s = (i / Dd) / Bb;
  int qi = qidx[0];
  y[i] = x[i] + qew[(size_t)qi * Ss * Dd + (size_t)s * Dd + d];
}

__global__ void k_copy(const float* __restrict__ a, float* __restrict__ b, int n) {
  int i = blockIdx.x * 256 + threadIdx.x;
  if (i < n) b[i] = a[i];
}

// H:(S,B,D) fp32 -> out:(B,C,48,48) fp32
__global__ void k_unpatch(const float* __restrict__ h, float* __restrict__ out) {
  int i = blockIdx.x * 256 + threadIdx.x;
  if (i >= Bb * Cc * IMGi * IMGi) return;
  int j = i % IMGi, t = i / IMGi;
  int r = t % IMGi; t /= IMGi;
  int c = t % Cc;
  int b = t / Cc;
  int g1 = r / Pp, p1 = r % Pp, g2 = j / Pp, p2 = j % Pp;
  int s = g1 * Gg + g2;
  int d = c * 9 + p1 * 3 + p2;
  out[i] = h[(size_t)(s * Bb + b) * Dd + d];
}

// ---------------- layernorm: one block (256 thr) per row, D=576 ----------------
__global__ void k_ln(const float* __restrict__ x, const float* __restrict__ g,
                     const float* __restrict__ b, float* __restrict__ y) {
  __shared__ float r1[256], r2[256];
  int row = blockIdx.x, t = threadIdx.x;
  const float* xr = x + (size_t)row * Dd;
  float s = 0.f, s2 = 0.f;
  for (int i = t; i < Dd; i += 256) { float v = xr[i]; s += v; s2 += v * v; }
  r1[t] = s; r2[t] = s2; __syncthreads();
  for (int o = 128; o > 0; o >>= 1) {
    if (t < o) { r1[t] += r1[t + o]; r2[t] += r2[t + o]; }
    __syncthreads();
  }
  float mean = r1[0] / Dd;
  float var  = r2[0] / Dd - mean * mean;
  float inv  = rsqrtf(var + EPSf);
  float* yr = y + (size_t)row * Dd;
  for (int i = t; i < Dd; i += 256)
    yr[i] = (xr[i] - mean) * inv * g[i] + b[i];
}

// ---------------- GEMM: out[m, n] = act( X[m,:K] . Wq[n,:K] + bias + res ) ----------------
// W row-major (N x K) fp32, quantized inline with alpha[slot].
// All of M(=1024), N, K are multiples of 16.
__global__ void k_gemm(const float* __restrict__ X, int ldx,
                       const float* __restrict__ W,
                       const float* __restrict__ bias,
                       const float* __restrict__ res, int ldr,
                       float* __restrict__ out, int ldo,
                       int N, int K,
                       const float* __restrict__ alpha_p, int slot, int relu) {
  __shared__ float Xs[16][17], Ws[16][17];
  const float alpha = alpha_p[slot];
  int tx = threadIdx.x, ty = threadIdx.y;
  int m  = blockIdx.y * 16 + ty;
  int n0 = blockIdx.x * 16;
  int n  = n0 + tx;
  float acc = 0.f;
  for (int k0 = 0; k0 < K; k0 += 16) {
    Xs[ty][tx] = X[(size_t)m * ldx + k0 + tx];
    float w = W[(size_t)(n0 + ty) * K + k0 + tx];
    float q = rintf(fminf(7.f, fmaxf(-8.f, w / alpha)));
    Ws[ty][tx] = q * alpha;
    __syncthreads();
#pragma unroll
    for (int kk = 0; kk < 16; ++kk) acc += Xs[ty][kk] * Ws[tx][kk];
    __syncthreads();
  }
  float v = acc;
  if (bias) v += bias[n];
  if (res)  v += res[(size_t)m * ldr + n];
  if (relu) v = fmaxf(v, 0.f);
  out[(size_t)m * ldo + n] = v;
}

// ---------------- attention ----------------
// QKV layout: row (s*B+b), ld=1728; q cols [0,576), k cols [576,1152), v cols [1152,1728)
__global__ void k_scores(const float* __restrict__ QKV, float* __restrict__ att, float scale) {
  int idx = blockIdx.x * 256 + threadIdx.x;           // B*NH*S*S
  if (idx >= Bb * NHh * Ss * Ss) return;
  int ki = idx % Ss, t = idx / Ss;
  int qi = t % Ss; t /= Ss;
  int h = t % NHh, b = t / NHh;
  const float* q = QKV + (size_t)(qi * Bb + b) * 1728 + h * HDd;
  const float* k = QKV + (size_t)(ki * Bb + b) * 1728 + Dd + h * HDd;
  float s = 0.f;
#pragma unroll
  for (int d = 0; d < HDd; ++d) s += q[d] * k[d];
  att[idx] = s * scale;
}

__global__ void k_softmax(float* __restrict__ att) {
  __shared__ float red[256];
  int row = blockIdx.x, t = threadIdx.x;
  float* p = att + (size_t)row * Ss;
  float v = p[t];
  red[t] = v; __syncthreads();
  for (int o = 128; o > 0; o >>= 1) {
    if (t < o) red[t] = fmaxf(red[t], red[t + o]);
    __syncthreads();
  }
  float mx = red[0]; __syncthreads();
  float e = __expf(v - mx);
  red[t] = e; __syncthreads();
  for (int o = 128; o > 0; o >>= 1) {
    if (t < o) red[t] += red[t + o];
    __syncthreads();
  }
  p[t] = e / red[0];
}

__global__ void k_av(const float* __restrict__ att, const float* __restrict__ QKV,
                     float* __restrict__ ctx) {
  int idx = blockIdx.x * 256 + threadIdx.x;           // M*D
  if (idx >= Mm * Dd) return;
  int d = idx % HDd, t = idx / HDd;
  int h = t % NHh; t /= NHh;
  int b = t % Bb;
  int qi = t / Bb;
  const float* a = att + (size_t)((b * NHh + h) * Ss + qi) * Ss;
  const float* vbase = QKV + 2 * Dd + h * HDd + d;
  float s = 0.f;
  for (int ki = 0; ki < Ss; ++ki) s += a[ki] * vbase[(size_t)(ki * Bb + b) * 1728];
  ctx[idx] = s;
}

// ---------------- host ----------------

extern "C" void kernel_launch(void* const* d_in, const int* in_sizes, int n_in,
                              void* d_out, int out_size, void* d_ws, size_t ws_size,
                              hipStream_t stream) {
  (void)in_sizes; (void)n_in; (void)out_size; (void)ws_size;
  const float* x            = (const float*)d_in[0];
  const float* lin_enc_w    = (const float*)d_in[1];
  const float* lin_enc_b    = (const float*)d_in[2];
  const float* pos_emb      = (const float*)d_in[3];
  const float* query_embed  = (const float*)d_in[4];
  const float* enc_in_w     = (const float*)d_in[5];
  const float* enc_out_w    = (const float*)d_in[6];
  const float* enc_l1_w     = (const float*)d_in[7];
  const float* enc_l1_b     = (const float*)d_in[8];
  const float* enc_l2_w     = (const float*)d_in[9];
  const float* enc_l2_b     = (const float*)d_in[10];
  const float* enc_ln1_g    = (const float*)d_in[11];
  const float* enc_ln1_b    = (const float*)d_in[12];
  const float* enc_ln2_g    = (const float*)d_in[13];
  const float* enc_ln2_b    = (const float*)d_in[14];
  const float* dec_sa_in_w  = (const float*)d_in[15];
  const float* dec_sa_out_w = (const float*)d_in[16];
  const float* dec_ca_in_w  = (const float*)d_in[17];
  const float* dec_ca_out_w = (const float*)d_in[18];
  const float* dec_l1_w     = (const float*)d_in[19];
  const float* dec_l1_b     = (const float*)d_in[20];
  const float* dec_l2_w     = (const float*)d_in[21];
  const float* dec_l2_b     = (const float*)d_in[22];
  const float* dec_ln1_g    = (const float*)d_in[23];
  const float* dec_ln1_b    = (const float*)d_in[24];
  const float* dec_ln2_g    = (const float*)d_in[25];
  const float* dec_ln2_b    = (const float*)d_in[26];
  const float* dec_ln3_g    = (const float*)d_in[27];
  const float* dec_ln3_b    = (const float*)d_in[28];
  const float* head1_w      = (const float*)d_in[29];
  const float* head1_b      = (const float*)d_in[30];
  const float* head2_w      = (const float*)d_in[31];
  const float* head2_b      = (const float*)d_in[32];
  const int*   query_idx    = (const int*)d_in[33];
  float* out = (float*)d_out;

  float* ws = (float*)d_ws;
  float* ABSUM = ws;
  float* ALPHA = ws + 64;
  float* H   = ws + 128;
  float* MEM = H   + Mm * Dd;
  float* LN  = MEM + Mm * Dd;
  float* LNQ = LN  + Mm * Dd;
  float* CTX = LNQ + Mm * Dd;
  float* QKV = CTX + Mm * Dd;
  float* ATT = QKV + Mm * HIDh;

  const int DD = Dd * Dd;            // 331776
  const int IN3 = 3 * Dd * Dd;       // 995328
  const int FF = HIDh * Dd;          // 1327104

  // ---- quantization scales ----
  QJobs jobs;
  int j = 0;
  jobs.ptr[j] = lin_enc_w; jobs.n[j] = DD; j++;                                    // 0
  for (int l = 0; l < NLl; ++l) { jobs.ptr[j] = enc_in_w  + (size_t)l * IN3; jobs.n[j] = IN3; j++; } // 1..4
  for (int l = 0; l < NLl; ++l) { jobs.ptr[j] = enc_out_w + (size_t)l * DD;  jobs.n[j] = DD;  j++; } // 5..8
  for (int l = 0; l < NLl; ++l) { jobs.ptr[j] = enc_l1_w  + (size_t)l * FF;  jobs.n[j] = FF;  j++; } // 9..12
  for (int l = 0; l < NLl; ++l) { jobs.ptr[j] = enc_l2_w  + (size_t)l * FF;  jobs.n[j] = FF;  j++; } // 13..16
  for (int l = 0; l < NLl; ++l) { jobs.ptr[j] = dec_sa_in_w  + (size_t)l * IN3; jobs.n[j] = IN3; j++; } // 17..20
  for (int l = 0; l < NLl; ++l) { jobs.ptr[j] = dec_sa_out_w + (size_t)l * DD;  jobs.n[j] = DD;  j++; } // 21..24
  for (int l = 0; l < NLl; ++l) { jobs.ptr[j] = dec_ca_in_w  + (size_t)l * IN3; jobs.n[j] = IN3; j++; } // 25..28
  for (int l = 0; l < NLl; ++l) { jobs.ptr[j] = dec_ca_out_w + (size_t)l * DD;  jobs.n[j] = DD;  j++; } // 29..32
  for (int l = 0; l < NLl; ++l) { jobs.ptr[j] = dec_l1_w + (size_t)l * FF; jobs.n[j] = FF; j++; }      // 33..36
  for (int l = 0; l < NLl; ++l) { jobs.ptr[j] = dec_l2_w + (size_t)l * FF; jobs.n[j] = FF; j++; }      // 37..40
  jobs.ptr[j] = head1_w; jobs.n[j] = FF; j++;                                     // 41
  jobs.ptr[j] = head2_w; jobs.n[j] = FF; j++;                                     // 42

  k_zero<<<1, 64, 0, stream>>>(ABSUM, 64);
  k_abssum<<<NJOBS * 64, 256, 0, stream>>>(jobs, ABSUM);
  k_alpha<<<1, 64, 0, stream>>>(jobs, ABSUM, ALPHA);

  auto gemm = [&](const float* X, int ldx, const float* W, int slot,
                  const float* bias, const float* res, int ldr,
                  float* o, int ldo, int N, int K, int relu) {
    dim3 grid(N / 16, Mm / 16), block(16, 16);
    k_gemm<<<grid, block, 0, stream>>>(X, ldx, W, bias, res, ldr, o, ldo, N, K, ALPHA, slot, relu);
  };

  const float scale = 1.f / sqrtf((float)HDd);
  auto attn = [&](const float* out_w, int out_slot) {
    k_scores<<<(Bb * NHh * Ss * Ss) / 256, 256, 0, stream>>>(QKV, ATT, scale);
    k_softmax<<<Bb * NHh * Ss, 256, 0, stream>>>(ATT);
    k_av<<<(Mm * Dd) / 256, 256, 0, stream>>>(ATT, QKV, CTX);
    gemm(CTX, Dd, out_w, out_slot, nullptr, H, Dd, H, Dd, Dd, Dd, 0);
  };

  const int NELEM = Mm * Dd;
  const int EB = (NELEM + 255) / 256;

  // ---- stem ----
  k_patchify<<<EB, 256, 0, stream>>>(x, LN);                 // LN holds t
  gemm(LN, Dd, lin_enc_w, 0, lin_enc_b, LN, Dd, H, Dd, Dd, Dd, 0);
  k_add_pos<<<EB, 256, 0, stream>>>(H, pos_emb);

  // ---- encoder ----
  for (int l = 0; l < NLl; ++l) {
    k_ln<<<Mm, 256, 0, stream>>>(H, enc_ln1_g + l * Dd, enc_ln1_b + l * Dd, LN);
    gemm(LN, Dd, enc_in_w + (size_t)l * IN3, 1 + l, nullptr, nullptr, 0, QKV, 1728, 1728, Dd, 0);
    attn(enc_out_w + (size_t)l * DD, 5 + l);
    k_ln<<<Mm, 256, 0, stream>>>(H, enc_ln2_g + l * Dd, enc_ln2_b + l * Dd, LN);
    gemm(LN, Dd, enc_l1_w + (size_t)l * FF, 9 + l, enc_l1_b + l * HIDh, nullptr, 0, QKV, HIDh, HIDh, Dd, 1);
    gemm(QKV, HIDh, enc_l2_w + (size_t)l * FF, 13 + l, enc_l2_b + l * Dd, H, Dd, H, Dd, Dd, HIDh, 0);
  }
  k_copy<<<EB, 256, 0, stream>>>(H, MEM, NELEM);

  // ---- decoder ----
  for (int l = 0; l < NLl; ++l) {
    // self-attn: q=k=ln+qe, v=ln
    k_ln<<<Mm, 256, 0, stream>>>(H, dec_ln1_g + l * Dd, dec_ln1_b + l * Dd, LN);
    k_add_qe<<<EB, 256, 0, stream>>>(LN, query_embed, query_idx, LNQ);
    gemm(LNQ, Dd, dec_sa_in_w + (size_t)l * IN3, 17 + l, nullptr, nullptr, 0, QKV, 1728, 2 * Dd, Dd, 0);
    gemm(LN,  Dd, dec_sa_in_w + (size_t)l * IN3 + (size_t)2 * Dd * Dd, 17 + l, nullptr, nullptr, 0, QKV + 2 * Dd, 1728, Dd, Dd, 0);
    attn(dec_sa_out_w + (size_t)l * DD, 21 + l);
    // cross-attn: q=ln+qe, k=v=mem
    k_ln<<<Mm, 256, 0, stream>>>(H, dec_ln2_g + l * Dd, dec_ln2_b + l * Dd, LN);
    k_add_qe<<<EB, 256, 0, stream>>>(LN, query_embed, query_idx, LNQ);
    gemm(LNQ, Dd, dec_ca_in_w + (size_t)l * IN3, 25 + l, nullptr, nullptr, 0, QKV, 1728, Dd, Dd, 0);
    gemm(MEM, Dd, dec_ca_in_w + (size_t)l * IN3 + (size_t)Dd * Dd, 25 + l, nullptr, nullptr, 0, QKV + Dd, 1728, 2 * Dd, Dd, 0);
    attn(dec_ca_out_w + (size_t)l * DD, 29 + l);
    // ffn
    k_ln<<<Mm, 256, 0, stream>>>(H, dec_ln3_g + l * Dd, dec_ln3_b + l * Dd, LN);
    gemm(LN, Dd, dec_l1_w + (size_t)l * FF, 33 + l, dec_l1_b + l * HIDh, nullptr, 0, QKV, HIDh, HIDh, Dd, 1);
    gemm(QKV, HIDh, dec_l2_w + (size_t)l * FF, 37 + l, dec_l2_b + l * Dd, H, Dd, H, Dd, Dd, HIDh, 0);
  }

  // ---- head ----
  gemm(H, Dd, head1_w, 41, head1_b, nullptr, 0, QKV, HIDh, HIDh, Dd, 1);
  gemm(QKV, HIDh, head2_w, 42, head2_b, H, Dd, H, Dd, Dd, HIDh, 0);

  // ---- output ----
  k_unpatch<<<EB, 256, 0, stream>>>(H, out);
}

// Round 3
// 3301.339 us; speedup vs baseline: 2.3647x; 2.3647x over previous
//
#include <hip/hip_runtime.h>
#include <cstddef>

#define Pp    3
#define Cc    64
#define IMGi  48
#define Gg    16
#define Dd    576
#define NHh   12
#define HDd   48
#define HIDh  2304
#define NLl   4
#define Ss    256
#define Bb    4
#define Mm    1024          // S*B tokens
#define EPSf  1e-5f
#define NJOBS 43

typedef short short8 __attribute__((ext_vector_type(8)));
typedef float f32x4  __attribute__((ext_vector_type(4)));

struct QJobs { const float* ptr[NJOBS]; int n[NJOBS]; int off[NJOBS]; };

// float -> bf16 (RNE), bit-level to avoid type-support surprises
__device__ __forceinline__ short f2bf(float f) {
  unsigned u = __float_as_uint(f);
  u = u + 0x7fffu + ((u >> 16) & 1u);
  return (short)(u >> 16);
}

// ---------------- small utility kernels ----------------

__global__ void k_zero(float* p, int n) {
  int i = blockIdx.x * blockDim.x + threadIdx.x;
  if (i < n) p[i] = 0.f;
}

__global__ void k_abssum(QJobs jobs, float* absum) {
  int job = blockIdx.x >> 6, blk = blockIdx.x & 63;
  const float* p = jobs.ptr[job];
  int n = jobs.n[job];
  float s = 0.f;
  for (int i = blk * 256 + threadIdx.x; i < n; i += 64 * 256)
    s += fabsf(p[i]);
  __shared__ float red[256];
  red[threadIdx.x] = s; __syncthreads();
  for (int o = 128; o > 0; o >>= 1) {
    if (threadIdx.x < o) red[threadIdx.x] += red[threadIdx.x + o];
    __syncthreads();
  }
  if (threadIdx.x == 0) atomicAdd(&absum[job], red[0]);
}

__global__ void k_alpha(QJobs jobs, const float* absum, float* alpha, float* inva) {
  int j = threadIdx.x;
  if (j < NJOBS) {
    float a = 2.f * (absum[j] / (float)jobs.n[j]) / sqrtf(7.f);
    alpha[j] = a;
    inva[j] = 1.f / a;
  }
}

// pre-quantize all weights: wq = bf16( rint(clamp(w/alpha,-8,7)) )  (q exact in bf16)
__global__ void k_quant(QJobs jobs, const float* __restrict__ inva, short* __restrict__ wq) {
  int job = blockIdx.x >> 7, blk = blockIdx.x & 127;
  const float* p = jobs.ptr[job];
  int n = jobs.n[job];
  short* dst = wq + (size_t)jobs.off[job];
  float ia = inva[job];
  for (int i = blk * 256 + threadIdx.x; i < n; i += 128 * 256) {
    float q = rintf(fminf(7.f, fmaxf(-8.f, p[i] * ia)));
    dst[i] = f2bf(q);
  }
}

// x:(B,C,48,48) fp32 -> t:(S,B,D) fp32 ; row = s*B+b
__global__ void k_patchify(const float* __restrict__ x, float* __restrict__ t) {
  int i = blockIdx.x * 256 + threadIdx.x;
  if (i >= Mm * Dd) return;
  int d = i % Dd, row = i / Dd;
  int b = row % Bb, s = row / Bb;
  int c = d / 9, r = d % 9;
  int p1 = r / 3, p2 = r % 3;
  int g1 = s / Gg, g2 = s % Gg;
  t[i] = x[((size_t)(b * Cc + c) * IMGi + (g1 * Pp + p1)) * IMGi + (g2 * Pp + p2)];
}

__global__ void k_add_pos(float* __restrict__ h, const float* __restrict__ pos) {
  int i = blockIdx.x * 256 + threadIdx.x;
  if (i >= Mm * Dd) return;
  int d = i % Dd, s = (i / Dd) / Bb;
  h[i] += pos[(size_t)s * Dd + d];
}

__global__ void k_add_qe(const float* __restrict__ x, const float* __restrict__ qew,
                         const int* __restrict__ qidx, float* __restrict__ y) {
  int i = blockIdx.x * 256 + threadIdx.x;
  if (i >= Mm * Dd) return;
  int d = i % Dd, s = (i / Dd) / Bb;
  int qi = qidx[0];
  y[i] = x[i] + qew[(size_t)qi * Ss * Dd + (size_t)s * Dd + d];
}

__global__ void k_copy(const float* __restrict__ a, float* __restrict__ b, int n) {
  int i = blockIdx.x * 256 + threadIdx.x;
  if (i < n) b[i] = a[i];
}

// H:(S,B,D) fp32 -> out:(B,C,48,48) fp32
__global__ void k_unpatch(const float* __restrict__ h, float* __restrict__ out) {
  int i = blockIdx.x * 256 + threadIdx.x;
  if (i >= Bb * Cc * IMGi * IMGi) return;
  int j = i % IMGi, t = i / IMGi;
  int r = t % IMGi; t /= IMGi;
  int c = t % Cc;
  int b = t / Cc;
  int g1 = r / Pp, p1 = r % Pp, g2 = j / Pp, p2 = j % Pp;
  int s = g1 * Gg + g2;
  int d = c * 9 + p1 * 3 + p2;
  out[i] = h[(size_t)(s * Bb + b) * Dd + d];
}

// ---------------- layernorm ----------------
__global__ void k_ln(const float* __restrict__ x, const float* __restrict__ g,
                     const float* __restrict__ b, float* __restrict__ y) {
  __shared__ float r1[256], r2[256];
  int row = blockIdx.x, t = threadIdx.x;
  const float* xr = x + (size_t)row * Dd;
  float s = 0.f, s2 = 0.f;
  for (int i = t; i < Dd; i += 256) { float v = xr[i]; s += v; s2 += v * v; }
  r1[t] = s; r2[t] = s2; __syncthreads();
  for (int o = 128; o > 0; o >>= 1) {
    if (t < o) { r1[t] += r1[t + o]; r2[t] += r2[t + o]; }
    __syncthreads();
  }
  float mean = r1[0] / Dd;
  float var  = r2[0] / Dd - mean * mean;
  float inv  = rsqrtf(var + EPSf);
  float* yr = y + (size_t)row * Dd;
  for (int i = t; i < Dd; i += 256)
    yr[i] = (xr[i] - mean) * inv * g[i] + b[i];
}

// ---------------- MFMA GEMM ----------------
// out[m,n] = act( alpha * sum_k X[m,k]*q[n,k] + bias[n] + res[m,n] )
// X fp32 (M x K, ld=ldx). Weights either pre-quantized bf16 q (Wq) or raw fp32 (Wraw,
// quantized inline). M=1024, N mult of 64, K mult of 32.
// Block: 256 thr = 4 waves; tile 64x64; wave quadrant 32x32 via 2x2 mfma_f32_16x16x32_bf16.
#define MT 64
#define NT 64
#define BK 32
#define LDSP 40   // padded row stride (shorts): 80B -> 2-way bank aliasing (free)

__global__ __launch_bounds__(256)
void k_gemm_mfma(const float* __restrict__ X, int ldx,
                 const float* __restrict__ Wraw,
                 const short* __restrict__ Wq,
                 const float* __restrict__ bias,
                 const float* res, int ldr,
                 float* out, int ldo,
                 int N, int K,
                 const float* __restrict__ alpha_p, const float* __restrict__ inva_p,
                 int slot, int relu)
{
  __shared__ short As[MT][LDSP];
  __shared__ short Bs[NT][LDSP];
  const int tid  = threadIdx.x;
  const int wave = tid >> 6, lane = tid & 63;
  const int quad = lane >> 4, l15 = lane & 15;
  const int tile_m = blockIdx.y * MT, tile_n = blockIdx.x * NT;
  const int m_off = (wave >> 1) * 32, n_off = (wave & 1) * 32;
  const int sr = tid >> 2;          // staging row 0..63
  const int sc = (tid & 3) * 8;     // staging k offset 0/8/16/24
  const float inva = inva_p[slot];

  f32x4 acc00 = {0,0,0,0}, acc01 = {0,0,0,0}, acc10 = {0,0,0,0}, acc11 = {0,0,0,0};

  for (int k0 = 0; k0 < K; k0 += BK) {
    // stage A: fp32 -> bf16
    const float* ax = X + (size_t)(tile_m + sr) * ldx + k0 + sc;
    float4 a0 = *(const float4*)ax;
    float4 a1 = *(const float4*)(ax + 4);
    short8 av;
    av[0] = f2bf(a0.x); av[1] = f2bf(a0.y); av[2] = f2bf(a0.z); av[3] = f2bf(a0.w);
    av[4] = f2bf(a1.x); av[5] = f2bf(a1.y); av[6] = f2bf(a1.z); av[7] = f2bf(a1.w);
    // stage B: q as bf16 (integer values, exact)
    short8 bv;
    if (Wq) {
      bv = *(const short8*)(Wq + (size_t)(tile_n + sr) * K + k0 + sc);
    } else {
      const float* wx = Wraw + (size_t)(tile_n + sr) * K + k0 + sc;
      float4 w0 = *(const float4*)wx;
      float4 w1 = *(const float4*)(wx + 4);
      bv[0] = f2bf(rintf(fminf(7.f, fmaxf(-8.f, w0.x * inva))));
      bv[1] = f2bf(rintf(fminf(7.f, fmaxf(-8.f, w0.y * inva))));
      bv[2] = f2bf(rintf(fminf(7.f, fmaxf(-8.f, w0.z * inva))));
      bv[3] = f2bf(rintf(fminf(7.f, fmaxf(-8.f, w0.w * inva))));
      bv[4] = f2bf(rintf(fminf(7.f, fmaxf(-8.f, w1.x * inva))));
      bv[5] = f2bf(rintf(fminf(7.f, fmaxf(-8.f, w1.y * inva))));
      bv[6] = f2bf(rintf(fminf(7.f, fmaxf(-8.f, w1.z * inva))));
      bv[7] = f2bf(rintf(fminf(7.f, fmaxf(-8.f, w1.w * inva))));
    }
    *(short8*)&As[sr][sc] = av;
    *(short8*)&Bs[sr][sc] = bv;
    __syncthreads();
    short8 af0 = *(short8*)&As[m_off + l15][quad * 8];
    short8 af1 = *(short8*)&As[m_off + 16 + l15][quad * 8];
    short8 bf0 = *(short8*)&Bs[n_off + l15][quad * 8];
    short8 bf1 = *(short8*)&Bs[n_off + 16 + l15][quad * 8];
    acc00 = __builtin_amdgcn_mfma_f32_16x16x32_bf16(af0, bf0, acc00, 0, 0, 0);
    acc01 = __builtin_amdgcn_mfma_f32_16x16x32_bf16(af0, bf1, acc01, 0, 0, 0);
    acc10 = __builtin_amdgcn_mfma_f32_16x16x32_bf16(af1, bf0, acc10, 0, 0, 0);
    acc11 = __builtin_amdgcn_mfma_f32_16x16x32_bf16(af1, bf1, acc11, 0, 0, 0);
    __syncthreads();
  }

  const float a_s = alpha_p[slot];
  const int rowb = tile_m + m_off + quad * 4;
  const int colb = tile_n + n_off + l15;
  // C/D layout (16x16x32 bf16): col = lane&15, row = quad*4 + reg   [measured m89/m91]
  f32x4 accs[4] = {acc00, acc01, acc10, acc11};
  #pragma unroll
  for (int t = 0; t < 4; ++t) {
    int row = rowb + ((t >> 1) * 16);
    int col = colb + ((t & 1) * 16);
    float bv = bias ? bias[col] : 0.f;
    #pragma unroll
    for (int r = 0; r < 4; ++r) {
      float v = accs[t][r] * a_s + bv;
      if (res)  v += res[(size_t)(row + r) * ldr + col];
      if (relu) v = fmaxf(v, 0.f);
      out[(size_t)(row + r) * ldo + col] = v;
    }
  }
}

// ---------------- attention ----------------
__global__ void k_scores(const float* __restrict__ QKV, float* __restrict__ att, float scale) {
  int idx = blockIdx.x * 256 + threadIdx.x;           // B*NH*S*S
  if (idx >= Bb * NHh * Ss * Ss) return;
  int ki = idx % Ss, t = idx / Ss;
  int qi = t % Ss; t /= Ss;
  int h = t % NHh, b = t / NHh;
  const float* q = QKV + (size_t)(qi * Bb + b) * 1728 + h * HDd;
  const float* k = QKV + (size_t)(ki * Bb + b) * 1728 + Dd + h * HDd;
  float s = 0.f;
#pragma unroll
  for (int d = 0; d < HDd; ++d) s += q[d] * k[d];
  att[idx] = s * scale;
}

__global__ void k_softmax(float* __restrict__ att) {
  __shared__ float red[256];
  int row = blockIdx.x, t = threadIdx.x;
  float* p = att + (size_t)row * Ss;
  float v = p[t];
  red[t] = v; __syncthreads();
  for (int o = 128; o > 0; o >>= 1) {
    if (t < o) red[t] = fmaxf(red[t], red[t + o]);
    __syncthreads();
  }
  float mx = red[0]; __syncthreads();
  float e = __expf(v - mx);
  red[t] = e; __syncthreads();
  for (int o = 128; o > 0; o >>= 1) {
    if (t < o) red[t] += red[t + o];
    __syncthreads();
  }
  p[t] = e / red[0];
}

__global__ void k_av(const float* __restrict__ att, const float* __restrict__ QKV,
                     float* __restrict__ ctx) {
  int idx = blockIdx.x * 256 + threadIdx.x;           // M*D
  if (idx >= Mm * Dd) return;
  int d = idx % HDd, t = idx / HDd;
  int h = t % NHh; t /= NHh;
  int b = t % Bb;
  int qi = t / Bb;
  const float* a = att + (size_t)((b * NHh + h) * Ss + qi) * Ss;
  const float* vbase = QKV + 2 * Dd + h * HDd + d;
  float s = 0.f;
  for (int ki = 0; ki < Ss; ++ki) s += a[ki] * vbase[(size_t)(ki * Bb + b) * 1728];
  ctx[idx] = s;
}

// ---------------- host ----------------

extern "C" void kernel_launch(void* const* d_in, const int* in_sizes, int n_in,
                              void* d_out, int out_size, void* d_ws, size_t ws_size,
                              hipStream_t stream) {
  (void)in_sizes; (void)n_in; (void)out_size;
  const float* x            = (const float*)d_in[0];
  const float* lin_enc_w    = (const float*)d_in[1];
  const float* lin_enc_b    = (const float*)d_in[2];
  const float* pos_emb      = (const float*)d_in[3];
  const float* query_embed  = (const float*)d_in[4];
  const float* enc_in_w     = (const float*)d_in[5];
  const float* enc_out_w    = (const float*)d_in[6];
  const float* enc_l1_w     = (const float*)d_in[7];
  const float* enc_l1_b     = (const float*)d_in[8];
  const float* enc_l2_w     = (const float*)d_in[9];
  const float* enc_l2_b     = (const float*)d_in[10];
  const float* enc_ln1_g    = (const float*)d_in[11];
  const float* enc_ln1_b    = (const float*)d_in[12];
  const float* enc_ln2_g    = (const float*)d_in[13];
  const float* enc_ln2_b    = (const float*)d_in[14];
  const float* dec_sa_in_w  = (const float*)d_in[15];
  const float* dec_sa_out_w = (const float*)d_in[16];
  const float* dec_ca_in_w  = (const float*)d_in[17];
  const float* dec_ca_out_w = (const float*)d_in[18];
  const float* dec_l1_w     = (const float*)d_in[19];
  const float* dec_l1_b     = (const float*)d_in[20];
  const float* dec_l2_w     = (const float*)d_in[21];
  const float* dec_l2_b     = (const float*)d_in[22];
  const float* dec_ln1_g    = (const float*)d_in[23];
  const float* dec_ln1_b    = (const float*)d_in[24];
  const float* dec_ln2_g    = (const float*)d_in[25];
  const float* dec_ln2_b    = (const float*)d_in[26];
  const float* dec_ln3_g    = (const float*)d_in[27];
  const float* dec_ln3_b    = (const float*)d_in[28];
  const float* head1_w      = (const float*)d_in[29];
  const float* head1_b      = (const float*)d_in[30];
  const float* head2_w      = (const float*)d_in[31];
  const float* head2_b      = (const float*)d_in[32];
  const int*   query_idx    = (const int*)d_in[33];
  float* out = (float*)d_out;

  const int DD  = Dd * Dd;           // 331776
  const int IN3 = 3 * Dd * Dd;       // 995328
  const int FF  = HIDh * Dd;         // 1327104
  const int MD  = Mm * Dd;           // 589824

  float* ws = (float*)d_ws;
  float* ABSUM = ws;          // 64
  float* ALPHA = ws + 64;     // 64
  float* INVA  = ws + 128;    // 64 (+64 pad)
  float* H   = ws + 256;
  float* MEM = H   + MD;
  float* LN  = MEM + MD;
  float* LNQ = LN  + MD;
  float* CTX = LNQ + MD;
  float* QKV = CTX + MD;                       // Mm x 2304 max
  float* ATT = QKV + (size_t)Mm * HIDh;        // B*NH*S*S
  size_t act_floats = 256 + 5 * (size_t)MD + (size_t)Mm * HIDh + (size_t)Bb * NHh * Ss * Ss;
  short* WQ = (short*)(ws + act_floats);
  const size_t WQ_ELEMS = (size_t)DD + 4 * ((size_t)IN3 + DD + FF + FF)
                        + 4 * ((size_t)IN3 + DD + IN3 + DD + FF + FF)
                        + 2 * (size_t)FF;      // 40,144,896
  const bool use_wq = ws_size >= act_floats * 4 + WQ_ELEMS * 2;

  // ---- job table (slot -> weight slice), offsets into WQ ----
  QJobs jobs;
  int j = 0; int off = 0;
  auto addjob = [&](const float* p, int n) { jobs.ptr[j] = p; jobs.n[j] = n; jobs.off[j] = off; off += n; j++; };
  addjob(lin_enc_w, DD);                                                    // 0
  for (int l = 0; l < NLl; ++l) addjob(enc_in_w  + (size_t)l * IN3, IN3);   // 1..4
  for (int l = 0; l < NLl; ++l) addjob(enc_out_w + (size_t)l * DD,  DD);    // 5..8
  for (int l = 0; l < NLl; ++l) addjob(enc_l1_w  + (size_t)l * FF,  FF);    // 9..12
  for (int l = 0; l < NLl; ++l) addjob(enc_l2_w  + (size_t)l * FF,  FF);    // 13..16
  for (int l = 0; l < NLl; ++l) addjob(dec_sa_in_w  + (size_t)l * IN3, IN3);// 17..20
  for (int l = 0; l < NLl; ++l) addjob(dec_sa_out_w + (size_t)l * DD,  DD); // 21..24
  for (int l = 0; l < NLl; ++l) addjob(dec_ca_in_w  + (size_t)l * IN3, IN3);// 25..28
  for (int l = 0; l < NLl; ++l) addjob(dec_ca_out_w + (size_t)l * DD,  DD); // 29..32
  for (int l = 0; l < NLl; ++l) addjob(dec_l1_w + (size_t)l * FF, FF);      // 33..36
  for (int l = 0; l < NLl; ++l) addjob(dec_l2_w + (size_t)l * FF, FF);      // 37..40
  addjob(head1_w, FF);                                                      // 41
  addjob(head2_w, FF);                                                      // 42

  k_zero<<<1, 64, 0, stream>>>(ABSUM, 64);
  k_abssum<<<NJOBS * 64, 256, 0, stream>>>(jobs, ABSUM);
  k_alpha<<<1, 64, 0, stream>>>(jobs, ABSUM, ALPHA, INVA);
  if (use_wq) k_quant<<<NJOBS * 128, 256, 0, stream>>>(jobs, INVA, WQ);

  // W = raw fp32 slice; wqsub = extra element offset within the slot's slice
  auto gemm = [&](const float* X, int ldx, const float* W, int slot, long wqsub,
                  const float* bias, const float* res, int ldr,
                  float* o, int ldo, int N, int K, int relu) {
    dim3 grid(N / NT, Mm / MT);
    const short* wq = use_wq ? WQ + (size_t)jobs.off[slot] + wqsub : nullptr;
    const float* wr = use_wq ? nullptr : W;
    k_gemm_mfma<<<grid, 256, 0, stream>>>(X, ldx, wr, wq, bias, res, ldr,
                                          o, ldo, N, K, ALPHA, INVA, slot, relu);
  };

  const float scale = 1.f / sqrtf((float)HDd);
  auto attn = [&](const float* out_w, int out_slot) {
    k_scores<<<(Bb * NHh * Ss * Ss) / 256, 256, 0, stream>>>(QKV, ATT, scale);
    k_softmax<<<Bb * NHh * Ss, 256, 0, stream>>>(ATT);
    k_av<<<(Mm * Dd) / 256, 256, 0, stream>>>(ATT, QKV, CTX);
    gemm(CTX, Dd, out_w, out_slot, 0, nullptr, H, Dd, H, Dd, Dd, Dd, 0);
  };

  const int NELEM = Mm * Dd;
  const int EB = (NELEM + 255) / 256;

  // ---- stem ----
  k_patchify<<<EB, 256, 0, stream>>>(x, LN);
  gemm(LN, Dd, lin_enc_w, 0, 0, lin_enc_b, LN, Dd, H, Dd, Dd, Dd, 0);
  k_add_pos<<<EB, 256, 0, stream>>>(H, pos_emb);

  // ---- encoder ----
  for (int l = 0; l < NLl; ++l) {
    k_ln<<<Mm, 256, 0, stream>>>(H, enc_ln1_g + l * Dd, enc_ln1_b + l * Dd, LN);
    gemm(LN, Dd, enc_in_w + (size_t)l * IN3, 1 + l, 0, nullptr, nullptr, 0, QKV, 1728, 1728, Dd, 0);
    attn(enc_out_w + (size_t)l * DD, 5 + l);
    k_ln<<<Mm, 256, 0, stream>>>(H, enc_ln2_g + l * Dd, enc_ln2_b + l * Dd, LN);
    gemm(LN, Dd, enc_l1_w + (size_t)l * FF, 9 + l, 0, enc_l1_b + l * HIDh, nullptr, 0, QKV, HIDh, HIDh, Dd, 1);
    gemm(QKV, HIDh, enc_l2_w + (size_t)l * FF, 13 + l, 0, enc_l2_b + l * Dd, H, Dd, H, Dd, Dd, HIDh, 0);
  }
  k_copy<<<EB, 256, 0, stream>>>(H, MEM, NELEM);

  // ---- decoder ----
  for (int l = 0; l < NLl; ++l) {
    // self-attn: q=k from ln+qe (rows 0..2D), v from ln (rows 2D..3D)
    k_ln<<<Mm, 256, 0, stream>>>(H, dec_ln1_g + l * Dd, dec_ln1_b + l * Dd, LN);
    k_add_qe<<<EB, 256, 0, stream>>>(LN, query_embed, query_idx, LNQ);
    gemm(LNQ, Dd, dec_sa_in_w + (size_t)l * IN3, 17 + l, 0,
         nullptr, nullptr, 0, QKV, 1728, 2 * Dd, Dd, 0);
    gemm(LN, Dd, dec_sa_in_w + (size_t)l * IN3 + (size_t)2 * Dd * Dd, 17 + l, (long)2 * Dd * Dd,
         nullptr, nullptr, 0, QKV + 2 * Dd, 1728, Dd, Dd, 0);
    attn(dec_sa_out_w + (size_t)l * DD, 21 + l);
    // cross-attn: q from ln+qe (rows 0..D), k,v from mem (rows D..3D)
    k_ln<<<Mm, 256, 0, stream>>>(H, dec_ln2_g + l * Dd, dec_ln2_b + l * Dd, LN);
    k_add_qe<<<EB, 256, 0, stream>>>(LN, query_embed, query_idx, LNQ);
    gemm(LNQ, Dd, dec_ca_in_w + (size_t)l * IN3, 25 + l, 0,
         nullptr, nullptr, 0, QKV, 1728, Dd, Dd, 0);
    gemm(MEM, Dd, dec_ca_in_w + (size_t)l * IN3 + (size_t)Dd * Dd, 25 + l, (long)Dd * Dd,
         nullptr, nullptr, 0, QKV + Dd, 1728, 2 * Dd, Dd, 0);
    attn(dec_ca_out_w + (size_t)l * DD, 29 + l);
    // ffn
    k_ln<<<Mm, 256, 0, stream>>>(H, dec_ln3_g + l * Dd, dec_ln3_b + l * Dd, LN);
    gemm(LN, Dd, dec_l1_w + (size_t)l * FF, 33 + l, 0, dec_l1_b + l * HIDh, nullptr, 0, QKV, HIDh, HIDh, Dd, 1);
    gemm(QKV, HIDh, dec_l2_w + (size_t)l * FF, 37 + l, 0, dec_l2_b + l * Dd, H, Dd, H, Dd, Dd, HIDh, 0);
  }

  // ---- head ----
  gemm(H, Dd, head1_w, 41, 0, head1_b, nullptr, 0, QKV, HIDh, HIDh, Dd, 1);
  gemm(QKV, HIDh, head2_w, 42, 0, head2_b, H, Dd, H, Dd, Dd, HIDh, 0);

  // ---- output ----
  k_unpatch<<<EB, 256, 0, stream>>>(H, out);
}

// Round 4
// 1650.906 us; speedup vs baseline: 4.7288x; 1.9997x over previous
//
#include <hip/hip_runtime.h>
#include <cstddef>

#define Pp    3
#define Cc    64
#define IMGi  48
#define Gg    16
#define Dd    576
#define NHh   12
#define HDd   48
#define HIDh  2304
#define NLl   4
#define Ss    256
#define Bb    4
#define Mm    1024          // S*B tokens
#define EPSf  1e-5f
#define NJOBS 43

typedef short short8 __attribute__((ext_vector_type(8)));
typedef short short4v __attribute__((ext_vector_type(4)));
typedef float f32x4  __attribute__((ext_vector_type(4)));

struct QJobs { const float* ptr[NJOBS]; int n[NJOBS]; int off[NJOBS]; };

// float -> bf16 (RNE), bit-level
__device__ __forceinline__ short f2bf(float f) {
  unsigned u = __float_as_uint(f);
  u = u + 0x7fffu + ((u >> 16) & 1u);
  return (short)(u >> 16);
}

// ---------------- small utility kernels ----------------

__global__ void k_zero(float* p, int n) {
  int i = blockIdx.x * blockDim.x + threadIdx.x;
  if (i < n) p[i] = 0.f;
}

__global__ void k_abssum(QJobs jobs, float* absum) {
  int job = blockIdx.x >> 6, blk = blockIdx.x & 63;
  const float* p = jobs.ptr[job];
  int n = jobs.n[job];
  float s = 0.f;
  for (int i = blk * 256 + threadIdx.x; i < n; i += 64 * 256)
    s += fabsf(p[i]);
  __shared__ float red[256];
  red[threadIdx.x] = s; __syncthreads();
  for (int o = 128; o > 0; o >>= 1) {
    if (threadIdx.x < o) red[threadIdx.x] += red[threadIdx.x + o];
    __syncthreads();
  }
  if (threadIdx.x == 0) atomicAdd(&absum[job], red[0]);
}

__global__ void k_alpha(QJobs jobs, const float* absum, float* alpha, float* inva) {
  int j = threadIdx.x;
  if (j < NJOBS) {
    float a = 2.f * (absum[j] / (float)jobs.n[j]) / sqrtf(7.f);
    alpha[j] = a;
    inva[j] = 1.f / a;
  }
}

// pre-quantize all weights: wq = bf16( rint(clamp(w/alpha,-8,7)) )  (q exact in bf16)
__global__ void k_quant(QJobs jobs, const float* __restrict__ inva, short* __restrict__ wq) {
  int job = blockIdx.x >> 7, blk = blockIdx.x & 127;
  const float* p = jobs.ptr[job];
  int n = jobs.n[job];
  short* dst = wq + (size_t)jobs.off[job];
  float ia = inva[job];
  for (int i = blk * 256 + threadIdx.x; i < n; i += 128 * 256) {
    float q = rintf(fminf(7.f, fmaxf(-8.f, p[i] * ia)));
    dst[i] = f2bf(q);
  }
}

// x:(B,C,48,48) fp32 -> t:(S,B,D) fp32 ; row = s*B+b
__global__ void k_patchify(const float* __restrict__ x, float* __restrict__ t) {
  int i = blockIdx.x * 256 + threadIdx.x;
  if (i >= Mm * Dd) return;
  int d = i % Dd, row = i / Dd;
  int b = row % Bb, s = row / Bb;
  int c = d / 9, r = d % 9;
  int p1 = r / 3, p2 = r % 3;
  int g1 = s / Gg, g2 = s % Gg;
  t[i] = x[((size_t)(b * Cc + c) * IMGi + (g1 * Pp + p1)) * IMGi + (g2 * Pp + p2)];
}

__global__ void k_add_pos(float* __restrict__ h, const float* __restrict__ pos) {
  int i = blockIdx.x * 256 + threadIdx.x;
  if (i >= Mm * Dd) return;
  int d = i % Dd, s = (i / Dd) / Bb;
  h[i] += pos[(size_t)s * Dd + d];
}

__global__ void k_add_qe(const float* __restrict__ x, const float* __restrict__ qew,
                         const int* __restrict__ qidx, float* __restrict__ y) {
  int i = blockIdx.x * 256 + threadIdx.x;
  if (i >= Mm * Dd) return;
  int d = i % Dd, s = (i / Dd) / Bb;
  int qi = qidx[0];
  y[i] = x[i] + qew[(size_t)qi * Ss * Dd + (size_t)s * Dd + d];
}

__global__ void k_copy(const float* __restrict__ a, float* __restrict__ b, int n) {
  int i = blockIdx.x * 256 + threadIdx.x;
  if (i < n) b[i] = a[i];
}

// H:(S,B,D) fp32 -> out:(B,C,48,48) fp32
__global__ void k_unpatch(const float* __restrict__ h, float* __restrict__ out) {
  int i = blockIdx.x * 256 + threadIdx.x;
  if (i >= Bb * Cc * IMGi * IMGi) return;
  int j = i % IMGi, t = i / IMGi;
  int r = t % IMGi; t /= IMGi;
  int c = t % Cc;
  int b = t / Cc;
  int g1 = r / Pp, p1 = r % Pp, g2 = j / Pp, p2 = j % Pp;
  int s = g1 * Gg + g2;
  int d = c * 9 + p1 * 3 + p2;
  out[i] = h[(size_t)(s * Bb + b) * Dd + d];
}

// ---------------- layernorm ----------------
__global__ void k_ln(const float* __restrict__ x, const float* __restrict__ g,
                     const float* __restrict__ b, float* __restrict__ y) {
  __shared__ float r1[256], r2[256];
  int row = blockIdx.x, t = threadIdx.x;
  const float* xr = x + (size_t)row * Dd;
  float s = 0.f, s2 = 0.f;
  for (int i = t; i < Dd; i += 256) { float v = xr[i]; s += v; s2 += v * v; }
  r1[t] = s; r2[t] = s2; __syncthreads();
  for (int o = 128; o > 0; o >>= 1) {
    if (t < o) { r1[t] += r1[t + o]; r2[t] += r2[t + o]; }
    __syncthreads();
  }
  float mean = r1[0] / Dd;
  float var  = r2[0] / Dd - mean * mean;
  float inv  = rsqrtf(var + EPSf);
  float* yr = y + (size_t)row * Dd;
  for (int i = t; i < Dd; i += 256)
    yr[i] = (xr[i] - mean) * inv * g[i] + b[i];
}

// ---------------- MFMA GEMM ----------------
#define MT 64
#define NT 64
#define BK 32
#define LDSP 40

__global__ __launch_bounds__(256)
void k_gemm_mfma(const float* __restrict__ X, int ldx,
                 const float* __restrict__ Wraw,
                 const short* __restrict__ Wq,
                 const float* __restrict__ bias,
                 const float* res, int ldr,
                 float* out, int ldo,
                 int N, int K,
                 const float* __restrict__ alpha_p, const float* __restrict__ inva_p,
                 int slot, int relu)
{
  __shared__ short As[MT][LDSP];
  __shared__ short Bs[NT][LDSP];
  const int tid  = threadIdx.x;
  const int wave = tid >> 6, lane = tid & 63;
  const int quad = lane >> 4, l15 = lane & 15;
  const int tile_m = blockIdx.y * MT, tile_n = blockIdx.x * NT;
  const int m_off = (wave >> 1) * 32, n_off = (wave & 1) * 32;
  const int sr = tid >> 2;
  const int sc = (tid & 3) * 8;
  const float inva = inva_p[slot];

  f32x4 acc00 = {0,0,0,0}, acc01 = {0,0,0,0}, acc10 = {0,0,0,0}, acc11 = {0,0,0,0};

  for (int k0 = 0; k0 < K; k0 += BK) {
    const float* ax = X + (size_t)(tile_m + sr) * ldx + k0 + sc;
    float4 a0 = *(const float4*)ax;
    float4 a1 = *(const float4*)(ax + 4);
    short8 av;
    av[0] = f2bf(a0.x); av[1] = f2bf(a0.y); av[2] = f2bf(a0.z); av[3] = f2bf(a0.w);
    av[4] = f2bf(a1.x); av[5] = f2bf(a1.y); av[6] = f2bf(a1.z); av[7] = f2bf(a1.w);
    short8 bv;
    if (Wq) {
      bv = *(const short8*)(Wq + (size_t)(tile_n + sr) * K + k0 + sc);
    } else {
      const float* wx = Wraw + (size_t)(tile_n + sr) * K + k0 + sc;
      float4 w0 = *(const float4*)wx;
      float4 w1 = *(const float4*)(wx + 4);
      bv[0] = f2bf(rintf(fminf(7.f, fmaxf(-8.f, w0.x * inva))));
      bv[1] = f2bf(rintf(fminf(7.f, fmaxf(-8.f, w0.y * inva))));
      bv[2] = f2bf(rintf(fminf(7.f, fmaxf(-8.f, w0.z * inva))));
      bv[3] = f2bf(rintf(fminf(7.f, fmaxf(-8.f, w0.w * inva))));
      bv[4] = f2bf(rintf(fminf(7.f, fmaxf(-8.f, w1.x * inva))));
      bv[5] = f2bf(rintf(fminf(7.f, fmaxf(-8.f, w1.y * inva))));
      bv[6] = f2bf(rintf(fminf(7.f, fmaxf(-8.f, w1.z * inva))));
      bv[7] = f2bf(rintf(fminf(7.f, fmaxf(-8.f, w1.w * inva))));
    }
    *(short8*)&As[sr][sc] = av;
    *(short8*)&Bs[sr][sc] = bv;
    __syncthreads();
    short8 af0 = *(short8*)&As[m_off + l15][quad * 8];
    short8 af1 = *(short8*)&As[m_off + 16 + l15][quad * 8];
    short8 bf0 = *(short8*)&Bs[n_off + l15][quad * 8];
    short8 bf1 = *(short8*)&Bs[n_off + 16 + l15][quad * 8];
    acc00 = __builtin_amdgcn_mfma_f32_16x16x32_bf16(af0, bf0, acc00, 0, 0, 0);
    acc01 = __builtin_amdgcn_mfma_f32_16x16x32_bf16(af0, bf1, acc01, 0, 0, 0);
    acc10 = __builtin_amdgcn_mfma_f32_16x16x32_bf16(af1, bf0, acc10, 0, 0, 0);
    acc11 = __builtin_amdgcn_mfma_f32_16x16x32_bf16(af1, bf1, acc11, 0, 0, 0);
    __syncthreads();
  }

  const float a_s = alpha_p[slot];
  const int rowb = tile_m + m_off + quad * 4;
  const int colb = tile_n + n_off + l15;
  f32x4 accs[4] = {acc00, acc01, acc10, acc11};
  #pragma unroll
  for (int t = 0; t < 4; ++t) {
    int row = rowb + ((t >> 1) * 16);
    int col = colb + ((t & 1) * 16);
    float bv = bias ? bias[col] : 0.f;
    #pragma unroll
    for (int r = 0; r < 4; ++r) {
      float v = accs[t][r] * a_s + bv;
      if (res)  v += res[(size_t)(row + r) * ldr + col];
      if (relu) v = fmaxf(v, 0.f);
      out[(size_t)(row + r) * ldo + col] = v;
    }
  }
}

// ---------------- fused flash attention ----------------
// grid: (S/64 q-tiles, B*NH). 256 thr = 4 waves; wave w owns 16 query cols.
// QKV row (s*B+b), ld=1728: q[0:576), k[576:1152), v[1152:1728). out: CTX (M x 576).
// S^T = K.Q^T via mfma (A=K m=ki, B=Q n=qi) -> softmax over ki in-register ->
// P via LDS (C-layout regs = 4 consecutive ki) -> O = P.V (A=P, B=V^T-in-LDS).
__global__ __launch_bounds__(256)
void k_attn(const float* __restrict__ QKV, float* __restrict__ ctx, float scale) {
  __shared__ short Ks[256][72];   // [ki][d]  d 48..63 zero-padded; stride 144B (16B mult)
  __shared__ short Qs[64][72];    // [qi][d]  zero-padded
  __shared__ short Vt[48][264];   // [d][ki]  stride 528B
  __shared__ short Pq[64][264];   // [qi][ki] stride 528B
  const int qt = blockIdx.x;
  const int b  = blockIdx.y / NHh, h = blockIdx.y % NHh;
  const int tid = threadIdx.x;
  const int w = tid >> 6, lane = tid & 63, quad = lane >> 4, l15 = lane & 15;

  // ---- stage K, V^T (row tid), Q (rows of this q-tile) ----
  {
    const float* kp = QKV + (size_t)(tid * Bb + b) * 1728 + Dd + h * HDd;
    #pragma unroll
    for (int d0 = 0; d0 < 48; d0 += 4) {
      float4 f = *(const float4*)(kp + d0);
      short4v v = { f2bf(f.x), f2bf(f.y), f2bf(f.z), f2bf(f.w) };
      *(short4v*)&Ks[tid][d0] = v;
    }
    short4v z = {0, 0, 0, 0};
    *(short4v*)&Ks[tid][48] = z; *(short4v*)&Ks[tid][52] = z;
    *(short4v*)&Ks[tid][56] = z; *(short4v*)&Ks[tid][60] = z;
    const float* vp = QKV + (size_t)(tid * Bb + b) * 1728 + 2 * Dd + h * HDd;
    #pragma unroll
    for (int d = 0; d < 48; ++d) Vt[d][tid] = f2bf(vp[d]);
    if (tid < 64) {
      const float* qp = QKV + (size_t)((qt * 64 + tid) * Bb + b) * 1728 + h * HDd;
      #pragma unroll
      for (int d0 = 0; d0 < 48; d0 += 4) {
        float4 f = *(const float4*)(qp + d0);
        short4v v = { f2bf(f.x), f2bf(f.y), f2bf(f.z), f2bf(f.w) };
        *(short4v*)&Qs[tid][d0] = v;
      }
      *(short4v*)&Qs[tid][48] = z; *(short4v*)&Qs[tid][52] = z;
      *(short4v*)&Qs[tid][56] = z; *(short4v*)&Qs[tid][60] = z;
    }
  }
  __syncthreads();

  // ---- scores: S^T fragments, 16 ki-tiles x (2 k-steps over d) ----
  short8 bq0 = *(short8*)&Qs[w * 16 + l15][quad * 8];
  short8 bq1 = *(short8*)&Qs[w * 16 + l15][32 + quad * 8];
  f32x4 sf[16];
  #pragma unroll
  for (int mt = 0; mt < 16; ++mt) {
    f32x4 acc = {0, 0, 0, 0};
    short8 a0 = *(short8*)&Ks[mt * 16 + l15][quad * 8];
    short8 a1 = *(short8*)&Ks[mt * 16 + l15][32 + quad * 8];
    acc = __builtin_amdgcn_mfma_f32_16x16x32_bf16(a0, bq0, acc, 0, 0, 0);
    acc = __builtin_amdgcn_mfma_f32_16x16x32_bf16(a1, bq1, acc, 0, 0, 0);
    sf[mt] = acc;
  }

  // ---- softmax over ki: local (16 tiles x 4 regs) + cross-quad lanes ^16,^32 ----
  float mx = -1e30f;
  #pragma unroll
  for (int mt = 0; mt < 16; ++mt)
    #pragma unroll
    for (int r = 0; r < 4; ++r) {
      sf[mt][r] *= scale;
      mx = fmaxf(mx, sf[mt][r]);
    }
  mx = fmaxf(mx, __shfl_xor(mx, 16));
  mx = fmaxf(mx, __shfl_xor(mx, 32));
  float sum = 0.f;
  #pragma unroll
  for (int mt = 0; mt < 16; ++mt)
    #pragma unroll
    for (int r = 0; r < 4; ++r) {
      float e = __expf(sf[mt][r] - mx);
      sf[mt][r] = e;
      sum += e;
    }
  sum += __shfl_xor(sum, 16);
  sum += __shfl_xor(sum, 32);
  float inv = 1.f / sum;

  // ---- write P (bf16) to LDS: regs 0..3 are consecutive ki ----
  #pragma unroll
  for (int mt = 0; mt < 16; ++mt) {
    short4v p = { f2bf(sf[mt][0] * inv), f2bf(sf[mt][1] * inv),
                  f2bf(sf[mt][2] * inv), f2bf(sf[mt][3] * inv) };
    *(short4v*)&Pq[w * 16 + l15][mt * 16 + quad * 4] = p;
  }
  __syncthreads();

  // ---- O = P.V : A=P[m=qi][k=ki], B=Vt (V^T) [k=ki][n=d], 8 k-steps, 3 d-tiles ----
  f32x4 of0 = {0,0,0,0}, of1 = {0,0,0,0}, of2 = {0,0,0,0};
  #pragma unroll
  for (int kt = 0; kt < 8; ++kt) {
    short8 a = *(short8*)&Pq[w * 16 + l15][kt * 32 + quad * 8];
    short8 b0 = *(short8*)&Vt[l15][kt * 32 + quad * 8];
    short8 b1 = *(short8*)&Vt[16 + l15][kt * 32 + quad * 8];
    short8 b2 = *(short8*)&Vt[32 + l15][kt * 32 + quad * 8];
    of0 = __builtin_amdgcn_mfma_f32_16x16x32_bf16(a, b0, of0, 0, 0, 0);
    of1 = __builtin_amdgcn_mfma_f32_16x16x32_bf16(a, b1, of1, 0, 0, 0);
    of2 = __builtin_amdgcn_mfma_f32_16x16x32_bf16(a, b2, of2, 0, 0, 0);
  }
  const int qg = qt * 64 + w * 16 + quad * 4;
  #pragma unroll
  for (int r = 0; r < 4; ++r) {
    float* cr = ctx + (size_t)((qg + r) * Bb + b) * Dd + h * HDd + l15;
    cr[0]  = of0[r];
    cr[16] = of1[r];
    cr[32] = of2[r];
  }
}

// ---------------- host ----------------

extern "C" void kernel_launch(void* const* d_in, const int* in_sizes, int n_in,
                              void* d_out, int out_size, void* d_ws, size_t ws_size,
                              hipStream_t stream) {
  (void)in_sizes; (void)n_in; (void)out_size;
  const float* x            = (const float*)d_in[0];
  const float* lin_enc_w    = (const float*)d_in[1];
  const float* lin_enc_b    = (const float*)d_in[2];
  const float* pos_emb      = (const float*)d_in[3];
  const float* query_embed  = (const float*)d_in[4];
  const float* enc_in_w     = (const float*)d_in[5];
  const float* enc_out_w    = (const float*)d_in[6];
  const float* enc_l1_w     = (const float*)d_in[7];
  const float* enc_l1_b     = (const float*)d_in[8];
  const float* enc_l2_w     = (const float*)d_in[9];
  const float* enc_l2_b     = (const float*)d_in[10];
  const float* enc_ln1_g    = (const float*)d_in[11];
  const float* enc_ln1_b    = (const float*)d_in[12];
  const float* enc_ln2_g    = (const float*)d_in[13];
  const float* enc_ln2_b    = (const float*)d_in[14];
  const float* dec_sa_in_w  = (const float*)d_in[15];
  const float* dec_sa_out_w = (const float*)d_in[16];
  const float* dec_ca_in_w  = (const float*)d_in[17];
  const float* dec_ca_out_w = (const float*)d_in[18];
  const float* dec_l1_w     = (const float*)d_in[19];
  const float* dec_l1_b     = (const float*)d_in[20];
  const float* dec_l2_w     = (const float*)d_in[21];
  const float* dec_l2_b     = (const float*)d_in[22];
  const float* dec_ln1_g    = (const float*)d_in[23];
  const float* dec_ln1_b    = (const float*)d_in[24];
  const float* dec_ln2_g    = (const float*)d_in[25];
  const float* dec_ln2_b    = (const float*)d_in[26];
  const float* dec_ln3_g    = (const float*)d_in[27];
  const float* dec_ln3_b    = (const float*)d_in[28];
  const float* head1_w      = (const float*)d_in[29];
  const float* head1_b      = (const float*)d_in[30];
  const float* head2_w      = (const float*)d_in[31];
  const float* head2_b      = (const float*)d_in[32];
  const int*   query_idx    = (const int*)d_in[33];
  float* out = (float*)d_out;

  const int DD  = Dd * Dd;
  const int IN3 = 3 * Dd * Dd;
  const int FF  = HIDh * Dd;
  const int MD  = Mm * Dd;

  float* ws = (float*)d_ws;
  float* ABSUM = ws;
  float* ALPHA = ws + 64;
  float* INVA  = ws + 128;
  float* H   = ws + 256;
  float* MEM = H   + MD;
  float* LN  = MEM + MD;
  float* LNQ = LN  + MD;
  float* CTX = LNQ + MD;
  float* QKV = CTX + MD;
  size_t act_floats = 256 + 5 * (size_t)MD + (size_t)Mm * HIDh;
  short* WQ = (short*)(ws + act_floats);
  const size_t WQ_ELEMS = (size_t)DD + 4 * ((size_t)IN3 + DD + FF + FF)
                        + 4 * ((size_t)IN3 + DD + IN3 + DD + FF + FF)
                        + 2 * (size_t)FF;
  const bool use_wq = ws_size >= act_floats * 4 + WQ_ELEMS * 2;

  QJobs jobs;
  int j = 0; int off = 0;
  auto addjob = [&](const float* p, int n) { jobs.ptr[j] = p; jobs.n[j] = n; jobs.off[j] = off; off += n; j++; };
  addjob(lin_enc_w, DD);
  for (int l = 0; l < NLl; ++l) addjob(enc_in_w  + (size_t)l * IN3, IN3);
  for (int l = 0; l < NLl; ++l) addjob(enc_out_w + (size_t)l * DD,  DD);
  for (int l = 0; l < NLl; ++l) addjob(enc_l1_w  + (size_t)l * FF,  FF);
  for (int l = 0; l < NLl; ++l) addjob(enc_l2_w  + (size_t)l * FF,  FF);
  for (int l = 0; l < NLl; ++l) addjob(dec_sa_in_w  + (size_t)l * IN3, IN3);
  for (int l = 0; l < NLl; ++l) addjob(dec_sa_out_w + (size_t)l * DD,  DD);
  for (int l = 0; l < NLl; ++l) addjob(dec_ca_in_w  + (size_t)l * IN3, IN3);
  for (int l = 0; l < NLl; ++l) addjob(dec_ca_out_w + (size_t)l * DD,  DD);
  for (int l = 0; l < NLl; ++l) addjob(dec_l1_w + (size_t)l * FF, FF);
  for (int l = 0; l < NLl; ++l) addjob(dec_l2_w + (size_t)l * FF, FF);
  addjob(head1_w, FF);
  addjob(head2_w, FF);

  k_zero<<<1, 64, 0, stream>>>(ABSUM, 64);
  k_abssum<<<NJOBS * 64, 256, 0, stream>>>(jobs, ABSUM);
  k_alpha<<<1, 64, 0, stream>>>(jobs, ABSUM, ALPHA, INVA);
  if (use_wq) k_quant<<<NJOBS * 128, 256, 0, stream>>>(jobs, INVA, WQ);

  auto gemm = [&](const float* X, int ldx, const float* W, int slot, long wqsub,
                  const float* bias, const float* res, int ldr,
                  float* o, int ldo, int N, int K, int relu) {
    dim3 grid(N / NT, Mm / MT);
    const short* wq = use_wq ? WQ + (size_t)jobs.off[slot] + wqsub : nullptr;
    const float* wr = use_wq ? nullptr : W;
    k_gemm_mfma<<<grid, 256, 0, stream>>>(X, ldx, wr, wq, bias, res, ldr,
                                          o, ldo, N, K, ALPHA, INVA, slot, relu);
  };

  const float scale = 1.f / sqrtf((float)HDd);
  auto attn = [&](const float* out_w, int out_slot) {
    k_attn<<<dim3(Ss / 64, Bb * NHh), 256, 0, stream>>>(QKV, CTX, scale);
    gemm(CTX, Dd, out_w, out_slot, 0, nullptr, H, Dd, H, Dd, Dd, Dd, 0);
  };

  const int NELEM = Mm * Dd;
  const int EB = (NELEM + 255) / 256;

  // ---- stem ----
  k_patchify<<<EB, 256, 0, stream>>>(x, LN);
  gemm(LN, Dd, lin_enc_w, 0, 0, lin_enc_b, LN, Dd, H, Dd, Dd, Dd, 0);
  k_add_pos<<<EB, 256, 0, stream>>>(H, pos_emb);

  // ---- encoder ----
  for (int l = 0; l < NLl; ++l) {
    k_ln<<<Mm, 256, 0, stream>>>(H, enc_ln1_g + l * Dd, enc_ln1_b + l * Dd, LN);
    gemm(LN, Dd, enc_in_w + (size_t)l * IN3, 1 + l, 0, nullptr, nullptr, 0, QKV, 1728, 1728, Dd, 0);
    attn(enc_out_w + (size_t)l * DD, 5 + l);
    k_ln<<<Mm, 256, 0, stream>>>(H, enc_ln2_g + l * Dd, enc_ln2_b + l * Dd, LN);
    gemm(LN, Dd, enc_l1_w + (size_t)l * FF, 9 + l, 0, enc_l1_b + l * HIDh, nullptr, 0, QKV, HIDh, HIDh, Dd, 1);
    gemm(QKV, HIDh, enc_l2_w + (size_t)l * FF, 13 + l, 0, enc_l2_b + l * Dd, H, Dd, H, Dd, Dd, HIDh, 0);
  }
  k_copy<<<EB, 256, 0, stream>>>(H, MEM, NELEM);

  // ---- decoder ----
  for (int l = 0; l < NLl; ++l) {
    k_ln<<<Mm, 256, 0, stream>>>(H, dec_ln1_g + l * Dd, dec_ln1_b + l * Dd, LN);
    k_add_qe<<<EB, 256, 0, stream>>>(LN, query_embed, query_idx, LNQ);
    gemm(LNQ, Dd, dec_sa_in_w + (size_t)l * IN3, 17 + l, 0,
         nullptr, nullptr, 0, QKV, 1728, 2 * Dd, Dd, 0);
    gemm(LN, Dd, dec_sa_in_w + (size_t)l * IN3 + (size_t)2 * Dd * Dd, 17 + l, (long)2 * Dd * Dd,
         nullptr, nullptr, 0, QKV + 2 * Dd, 1728, Dd, Dd, 0);
    attn(dec_sa_out_w + (size_t)l * DD, 21 + l);
    k_ln<<<Mm, 256, 0, stream>>>(H, dec_ln2_g + l * Dd, dec_ln2_b + l * Dd, LN);
    k_add_qe<<<EB, 256, 0, stream>>>(LN, query_embed, query_idx, LNQ);
    gemm(LNQ, Dd, dec_ca_in_w + (size_t)l * IN3, 25 + l, 0,
         nullptr, nullptr, 0, QKV, 1728, Dd, Dd, 0);
    gemm(MEM, Dd, dec_ca_in_w + (size_t)l * IN3 + (size_t)Dd * Dd, 25 + l, (long)Dd * Dd,
         nullptr, nullptr, 0, QKV + Dd, 1728, 2 * Dd, Dd, 0);
    attn(dec_ca_out_w + (size_t)l * DD, 29 + l);
    k_ln<<<Mm, 256, 0, stream>>>(H, dec_ln3_g + l * Dd, dec_ln3_b + l * Dd, LN);
    gemm(LN, Dd, dec_l1_w + (size_t)l * FF, 33 + l, 0, dec_l1_b + l * HIDh, nullptr, 0, QKV, HIDh, HIDh, Dd, 1);
    gemm(QKV, HIDh, dec_l2_w + (size_t)l * FF, 37 + l, 0, dec_l2_b + l * Dd, H, Dd, H, Dd, Dd, HIDh, 0);
  }

  // ---- head ----
  gemm(H, Dd, head1_w, 41, 0, head1_b, nullptr, 0, QKV, HIDh, HIDh, Dd, 1);
  gemm(QKV, HIDh, head2_w, 42, 0, head2_b, H, Dd, H, Dd, Dd, HIDh, 0);

  // ---- output ----
  k_unpatch<<<EB, 256, 0, stream>>>(H, out);
}